// Round 5
// baseline (653.681 us; speedup 1.0000x reference)
//
#include <hip/hip_runtime.h>
#include <hip/hip_bf16.h>

// GCN: 4 layers, D^{-1/2}(A+I)D^{-1/2} aggregation, log_softmax output.
// CSR built per call; u = dinv*(h@W) pre-scale, CSR gather sums, post-scale
// by dinv[dst], self-loop folded as +u[d]. Layer1/4 transform BEFORE agg.
// R1: k_fill/k_count latency-bound -> batched edges/thread.
// R3: W1 in LDS + 4-way k-split + partial reduce (740->623us).
// R4: agg16 serial col->gather chain -> 64-edge chunk: one coalesced col
//     load + shfl distribute + 4 concurrent gathers (dead lanes gather a
//     zeroed pad row). t768: register-double-buffered x tiles (issue t+1
//     loads before computing t). k_t4 vectorized.

#define DIVUP(a, b) (((a) + (b) - 1) / (b))

// ---------- edge dtype detection (int64 vs int32 ABI ambiguity) ----------
__global__ void k_detect(const void* ei, int* flag) {
    int t = threadIdx.x;  // 64 threads
    const int* p = (const int*)ei;
    bool z = (p[2 * t + 1] == 0);
    unsigned long long m = __ballot(z);
    if (t == 0) *flag = (m == ~0ULL) ? 1 : 0;
}

__device__ __forceinline__ int load_idx(const void* ei, int is64, size_t pos) {
    if (is64) return (int)((const long long*)ei)[pos];
    return ((const int*)ei)[pos];
}

// ---------- init: zero degree counts + u pad row ----------
__global__ void k_init(int* cnt, int n, float* u) {
    int i = blockIdx.x * 256 + threadIdx.x;
    if (i < n) cnt[i] = 0;
    if (blockIdx.x == 0 && threadIdx.x < 16) u[(size_t)n * 16 + threadIdx.x] = 0.f;
}

__global__ void k_count(const void* ei, const int* flag, int* cnt, int E) {
    int base = blockIdx.x * 2048 + threadIdx.x;
    int is64 = *flag;
    int d[8];
    bool ok[8];
#pragma unroll
    for (int j = 0; j < 8; ++j) {
        int e = base + j * 256;
        ok[j] = (e < E);
        d[j] = ok[j] ? load_idx(ei, is64, (size_t)E + e) : 0;
    }
#pragma unroll
    for (int j = 0; j < 8; ++j)
        if (ok[j]) atomicAdd(&cnt[d[j]], 1);
}

// ---------- exclusive scan (3-phase) ----------
__global__ void k_scanA(const int* cnt, int* offs, int* bsums, int n) {
    __shared__ int s[256];
    int t = threadIdx.x;
    int i = blockIdx.x * 256 + t;
    int v = (i < n) ? cnt[i] : 0;
    s[t] = v;
    __syncthreads();
    for (int off = 1; off < 256; off <<= 1) {
        int add = (t >= off) ? s[t - off] : 0;
        __syncthreads();
        s[t] += add;
        __syncthreads();
    }
    if (i < n) offs[i] = s[t] - v;
    if (t == 255) bsums[blockIdx.x] = s[t];
}

__global__ void k_scanB(int* bsums, int nb) {
    __shared__ int s[512];
    int t = threadIdx.x;
    int v = (t < nb) ? bsums[t] : 0;
    s[t] = v;
    __syncthreads();
    for (int off = 1; off < 512; off <<= 1) {
        int add = (t >= off) ? s[t - off] : 0;
        __syncthreads();
        s[t] += add;
        __syncthreads();
    }
    if (t < nb) bsums[t] = s[t] - v;
}

__global__ void k_scanC(int* offs, int* cursor, const int* bsums,
                        const int* cnt, float* dinv, int n) {
    int i = blockIdx.x * 256 + threadIdx.x;
    if (i >= n) return;
    int o = offs[i] + bsums[blockIdx.x];
    offs[i] = o;
    cursor[i] = o;
    dinv[i] = rsqrtf((float)(cnt[i] + 1));  // +1 self-loop
}

// ---------- CSR fill: 8 edges/thread ----------
__global__ void k_fill(const void* ei, const int* flag, int* cursor, int* col, int E) {
    int base = blockIdx.x * 2048 + threadIdx.x;
    int is64 = *flag;
    int s[8], d[8], p[8];
    bool ok[8];
#pragma unroll
    for (int j = 0; j < 8; ++j) {
        int e = base + j * 256;
        ok[j] = (e < E);
        s[j] = ok[j] ? load_idx(ei, is64, (size_t)e) : 0;
        d[j] = ok[j] ? load_idx(ei, is64, (size_t)E + e) : 0;
    }
#pragma unroll
    for (int j = 0; j < 8; ++j)
        p[j] = ok[j] ? atomicAdd(&cursor[d[j]], 1) : 0;
#pragma unroll
    for (int j = 0; j < 8; ++j)
        if (ok[j]) col[p[j]] = s[j];
}

__device__ __forceinline__ void fma4(float s, const float4 w, float4& a) {
    a.x = fmaf(s, w.x, a.x);
    a.y = fmaf(s, w.y, a.y);
    a.z = fmaf(s, w.z, a.z);
    a.w = fmaf(s, w.w, a.w);
}

// ---------- layer-1 transform, k-split, register-double-buffered ----------
// Block = 256 = 4 waves; blockIdx -> (nodeblock, slice of 192 k).
// W1 slice staged to LDS (padded stride 20). Per tile: issue next tile's
// 4 global loads into regs, compute current tile from LDS, then ds_write.
__global__ void k_transform768(const float* __restrict__ x, const float* __restrict__ W,
                               float* __restrict__ parts, int n) {
    __shared__ float Wl[192 * 20];      // 15360 B
    __shared__ float lx[4][16][68];     // 17408 B
    int slice = blockIdx.x & 3;
    int nblk = blockIdx.x >> 2;
    int tid = threadIdx.x;
    int wid = tid >> 6, lane = tid & 63;
    int nbase = nblk * 64 + wid * 16;
    int nloc = lane >> 2, og = lane & 3;
    int node = nbase + nloc;
    const float4* xg = (const float4*)x;
    const float4* wg = (const float4*)W;

#pragma unroll
    for (int i = tid; i < 768; i += 256) {
        float4 v = wg[slice * 768 + i];
        int k = i >> 2, g = i & 3;
        *(float4*)&Wl[k * 20 + g * 4] = v;
    }
    __syncthreads();

    float4 rg[4];
    const float4 z4 = {0.f, 0.f, 0.f, 0.f};
    // prologue: tile 0 -> regs -> LDS
#pragma unroll
    for (int r = 0; r < 4; ++r) {
        int f = r * 64 + lane, sr = f >> 4, sc = f & 15;
        int nb = nbase + sr;
        rg[r] = (nb < n) ? xg[(size_t)nb * 192 + slice * 48 + sc] : z4;
    }
#pragma unroll
    for (int r = 0; r < 4; ++r) {
        int f = r * 64 + lane, sr = f >> 4, sc = f & 15;
        *(float4*)&lx[wid][sr][sc * 4] = rg[r];
    }

    float4 acc = {0.f, 0.f, 0.f, 0.f};
    const float* lxr = lx[wid][nloc];
#pragma unroll 1
    for (int t = 0; t < 3; ++t) {
        if (t < 2) {  // issue next tile's loads (hidden under compute)
#pragma unroll
            for (int r = 0; r < 4; ++r) {
                int f = r * 64 + lane, sr = f >> 4, sc = f & 15;
                int nb = nbase + sr;
                rg[r] = (nb < n) ? xg[(size_t)nb * 192 + slice * 48 + (t + 1) * 16 + sc] : z4;
            }
        }
#pragma unroll 4
        for (int kk = 0; kk < 16; ++kk) {
            float4 xv = *(const float4*)&lxr[kk * 4];
            int kb = (t * 16 + kk) * 4;
            fma4(xv.x, *(const float4*)&Wl[(kb + 0) * 20 + og * 4], acc);
            fma4(xv.y, *(const float4*)&Wl[(kb + 1) * 20 + og * 4], acc);
            fma4(xv.z, *(const float4*)&Wl[(kb + 2) * 20 + og * 4], acc);
            fma4(xv.w, *(const float4*)&Wl[(kb + 3) * 20 + og * 4], acc);
        }
        if (t < 2) {  // wave-private LDS slice; per-wave DS order keeps RAW safe
#pragma unroll
            for (int r = 0; r < 4; ++r) {
                int f = r * 64 + lane, sr = f >> 4, sc = f & 15;
                *(float4*)&lx[wid][sr][sc * 4] = rg[r];
            }
        }
    }
    if (node < n) {
        float4* dst = (float4*)(parts + (size_t)slice * n * 16);
        dst[(size_t)node * 4 + og] = acc;
    }
}

// ---------- reduce 4 partials, apply dinv ----------
__global__ void k_red4(const float* __restrict__ parts, const float* __restrict__ dinv,
                       float* __restrict__ u, int n) {
    int g = blockIdx.x * 256 + threadIdx.x;
    if (g >= 4 * n) return;
    size_t stride = (size_t)n * 4;
    const float4* p = (const float4*)parts;
    float4 a = p[g], b = p[g + stride], c = p[g + 2 * stride], d = p[g + 3 * stride];
    float s = dinv[g >> 2];
    float4 r;
    r.x = (a.x + b.x + c.x + d.x) * s;
    r.y = (a.y + b.y + c.y + d.y) * s;
    r.z = (a.z + b.z + c.z + d.z) * s;
    r.w = (a.w + b.w + c.w + d.w) * s;
    ((float4*)u)[g] = r;
}

// ---------- 16->16 transform ----------
__global__ void k_transform16(const float* __restrict__ in, const float* __restrict__ W,
                              const float* __restrict__ dinv, float* __restrict__ out, int n) {
    int gid = blockIdx.x * 256 + threadIdx.x;
    int node = gid >> 2, og = gid & 3;
    if (node >= n) return;
    const float4* xr = (const float4*)(in + (size_t)node * 16);
    const float4* w4 = (const float4*)W;
    float4 acc = {0.f, 0.f, 0.f, 0.f};
#pragma unroll
    for (int kk = 0; kk < 4; ++kk) {
        float4 xv = xr[kk];
        int k4 = kk * 16;
        fma4(xv.x, w4[k4 + og], acc);
        fma4(xv.y, w4[k4 + 4 + og], acc);
        fma4(xv.z, w4[k4 + 8 + og], acc);
        fma4(xv.w, w4[k4 + 12 + og], acc);
    }
    float s = dinv[node];
    float4 r = {acc.x * s, acc.y * s, acc.z * s, acc.w * s};
    ((float4*)out)[(size_t)node * 4 + og] = r;
}

// ---------- layer-4 transform (vectorized loads) ----------
__global__ void k_t4(const float* __restrict__ h, const float* __restrict__ W4,
                     const float* __restrict__ dinv, float4* __restrict__ u4p, int n) {
    int node = blockIdx.x * 256 + threadIdx.x;
    if (node >= n) return;
    const float4* hr = (const float4*)(h + (size_t)node * 16);
    float4 h0 = hr[0], h1 = hr[1], h2 = hr[2], h3 = hr[3];
    float hv[16] = {h0.x, h0.y, h0.z, h0.w, h1.x, h1.y, h1.z, h1.w,
                    h2.x, h2.y, h2.z, h2.w, h3.x, h3.y, h3.z, h3.w};
    float a0 = 0.f, a1 = 0.f, a2 = 0.f;
#pragma unroll
    for (int k = 0; k < 16; ++k) {
        a0 = fmaf(hv[k], W4[k * 3 + 0], a0);
        a1 = fmaf(hv[k], W4[k * 3 + 1], a1);
        a2 = fmaf(hv[k], W4[k * 3 + 2], a2);
    }
    float s = dinv[node];
    u4p[node] = make_float4(a0 * s, a1 * s, a2 * s, 0.f);
}

// ---------- aggregate 16-dim via 64-edge chunks ----------
// One wave/node. col load coalesced over 64 edges, shfl distributes src
// indices to 16 edge-slots x 4 comps; 4 gathers concurrently in flight.
// Dead lanes gather the zeroed pad row u[n].
__global__ void k_agg16(const float* __restrict__ u, const int* __restrict__ col,
                        const int* __restrict__ offs, const int* __restrict__ cnt,
                        const float* __restrict__ dinv, const float* __restrict__ b,
                        float* __restrict__ hout, int n) {
    int wave = threadIdx.x >> 6;
    int node = blockIdx.x * 4 + wave;
    if (node >= n) return;
    int lane = threadIdx.x & 63;
    int eslot = lane >> 2, comp = lane & 3;
    const float4* u4 = (const float4*)u;
    int beg = offs[node], c = cnt[node];
    float4 a0 = {0.f, 0.f, 0.f, 0.f}, a1 = a0, a2 = a0, a3 = a0;
#pragma unroll 1
    for (int base = 0; base < c; base += 64) {
        int colv = col[beg + base + lane];  // 64 edges, one coalesced load
        int s0 = __shfl(colv, eslot, 64);
        int s1 = __shfl(colv, eslot + 16, 64);
        int s2 = __shfl(colv, eslot + 32, 64);
        int s3 = __shfl(colv, eslot + 48, 64);
        int rem = c - base;
        s0 = (eslot < rem) ? s0 : n;
        s1 = (eslot + 16 < rem) ? s1 : n;
        s2 = (eslot + 32 < rem) ? s2 : n;
        s3 = (eslot + 48 < rem) ? s3 : n;
        float4 v0 = u4[(size_t)s0 * 4 + comp];
        float4 v1 = u4[(size_t)s1 * 4 + comp];
        float4 v2 = u4[(size_t)s2 * 4 + comp];
        float4 v3 = u4[(size_t)s3 * 4 + comp];
        a0.x += v0.x; a0.y += v0.y; a0.z += v0.z; a0.w += v0.w;
        a1.x += v1.x; a1.y += v1.y; a1.z += v1.z; a1.w += v1.w;
        a2.x += v2.x; a2.y += v2.y; a2.z += v2.z; a2.w += v2.w;
        a3.x += v3.x; a3.y += v3.y; a3.z += v3.z; a3.w += v3.w;
    }
    a0.x += a1.x + a2.x + a3.x;
    a0.y += a1.y + a2.y + a3.y;
    a0.z += a1.z + a2.z + a3.z;
    a0.w += a1.w + a2.w + a3.w;
    for (int off = 4; off < 64; off <<= 1) {
        a0.x += __shfl_xor(a0.x, off, 64);
        a0.y += __shfl_xor(a0.y, off, 64);
        a0.z += __shfl_xor(a0.z, off, 64);
        a0.w += __shfl_xor(a0.w, off, 64);
    }
    if (eslot == 0) {
        float4 self = u4[(size_t)node * 4 + comp];
        float dv = dinv[node];
        float4 bb = ((const float4*)b)[comp];
        float4 r;
        r.x = fmaxf(fmaf(dv, a0.x + self.x, bb.x), 0.f);
        r.y = fmaxf(fmaf(dv, a0.y + self.y, bb.y), 0.f);
        r.z = fmaxf(fmaf(dv, a0.z + self.z, bb.z), 0.f);
        r.w = fmaxf(fmaf(dv, a0.w + self.w, bb.w), 0.f);
        ((float4*)hout)[(size_t)node * 4 + comp] = r;
    }
}

// ---------- final aggregate (3 dims) + bias + log_softmax ----------
__global__ void k_agg_out(const float4* __restrict__ u4p, const int* __restrict__ col,
                          const int* __restrict__ offs, const int* __restrict__ cnt,
                          const float* __restrict__ dinv, const float* __restrict__ b4,
                          float* __restrict__ out, int n) {
    int wave = threadIdx.x >> 6;
    int node = blockIdx.x * 4 + wave;
    if (node >= n) return;
    int lane = threadIdx.x & 63;
    int beg = offs[node], c = cnt[node];
    float a0 = 0.f, a1 = 0.f, a2 = 0.f;
    for (int i = lane; i < c; i += 64) {
        float4 v = u4p[col[beg + i]];
        a0 += v.x; a1 += v.y; a2 += v.z;
    }
    for (int off = 1; off < 64; off <<= 1) {
        a0 += __shfl_xor(a0, off, 64);
        a1 += __shfl_xor(a1, off, 64);
        a2 += __shfl_xor(a2, off, 64);
    }
    if (lane == 0) {
        float4 self = u4p[node];
        float dv = dinv[node];
        float v0 = fmaf(dv, a0 + self.x, b4[0]);
        float v1 = fmaf(dv, a1 + self.y, b4[1]);
        float v2 = fmaf(dv, a2 + self.z, b4[2]);
        float m = fmaxf(v0, fmaxf(v1, v2));
        float lse = m + logf(expf(v0 - m) + expf(v1 - m) + expf(v2 - m));
        out[(size_t)node * 3 + 0] = v0 - lse;
        out[(size_t)node * 3 + 1] = v1 - lse;
        out[(size_t)node * 3 + 2] = v2 - lse;
    }
}

extern "C" void kernel_launch(void* const* d_in, const int* in_sizes, int n_in,
                              void* d_out, int out_size, void* d_ws, size_t ws_size,
                              hipStream_t stream) {
    const float* x  = (const float*)d_in[0];
    const void*  ei = d_in[1];
    const float* W1 = (const float*)d_in[2];
    const float* b1 = (const float*)d_in[3];
    const float* W2 = (const float*)d_in[4];
    const float* b2 = (const float*)d_in[5];
    const float* W3 = (const float*)d_in[6];
    const float* b3 = (const float*)d_in[7];
    const float* W4 = (const float*)d_in[8];
    const float* b4 = (const float*)d_in[9];
    float* out = (float*)d_out;

    const int N = in_sizes[0] / 768;
    const int E = in_sizes[1] / 2;

    char* p = (char*)d_ws;
    auto alloc = [&](size_t bytes) {
        void* r = (void*)p;
        p += (bytes + 255) & ~(size_t)255;
        return r;
    };
    int*   cnt    = (int*)alloc((size_t)N * 4);
    int*   offs   = (int*)alloc((size_t)N * 4);
    int*   cursor = (int*)alloc((size_t)N * 4);
    int*   bsums  = (int*)alloc(4096);
    int*   flag   = (int*)alloc(256);
    float* dinv   = (float*)alloc((size_t)N * 4);
    int*   col    = (int*)alloc((size_t)(E + 64) * 4);      // +64 pad (read-only overrun)
    float* u      = (float*)alloc((size_t)(N + 1) * 16 * 4); // +1 zeroed pad row
    float* h      = (float*)alloc((size_t)N * 16 * 4);
    float4* u4p   = (float4*)alloc((size_t)N * 16);
    float* parts  = (float*)alloc((size_t)4 * N * 16 * 4);

    const int nbN = DIVUP(N, 256);
    const int nbE8 = DIVUP(E, 2048);
    const int nbT = DIVUP(4 * N, 256);
    const int nbA = DIVUP(N, 4);
    const int nbX = DIVUP(N, 64) * 4;

    k_detect<<<1, 64, 0, stream>>>(ei, flag);
    k_init<<<nbN, 256, 0, stream>>>(cnt, N, u);
    k_count<<<nbE8, 256, 0, stream>>>(ei, flag, cnt, E);
    k_scanA<<<nbN, 256, 0, stream>>>(cnt, offs, bsums, N);
    k_scanB<<<1, 512, 0, stream>>>(bsums, nbN);
    k_scanC<<<nbN, 256, 0, stream>>>(offs, cursor, bsums, cnt, dinv, N);
    k_fill<<<nbE8, 256, 0, stream>>>(ei, flag, cursor, col, E);

    // layer 1
    k_transform768<<<nbX, 256, 0, stream>>>(x, W1, parts, N);
    k_red4<<<nbT, 256, 0, stream>>>(parts, dinv, u, N);
    k_agg16<<<nbA, 256, 0, stream>>>(u, col, offs, cnt, dinv, b1, h, N);
    // layer 2
    k_transform16<<<nbT, 256, 0, stream>>>(h, W2, dinv, u, N);
    k_agg16<<<nbA, 256, 0, stream>>>(u, col, offs, cnt, dinv, b2, h, N);
    // layer 3
    k_transform16<<<nbT, 256, 0, stream>>>(h, W3, dinv, u, N);
    k_agg16<<<nbA, 256, 0, stream>>>(u, col, offs, cnt, dinv, b3, h, N);
    // layer 4
    k_t4<<<nbN, 256, 0, stream>>>(h, W4, dinv, u4p, N);
    k_agg_out<<<nbA, 256, 0, stream>>>(u4p, col, offs, cnt, dinv, b4, out, N);
}

// Round 6
// 406.981 us; speedup vs baseline: 1.6062x; 1.6062x over previous
//
#include <hip/hip_runtime.h>
#include <hip/hip_bf16.h>

// GCN: 4 layers, D^{-1/2}(A+I)D^{-1/2} aggregation, log_softmax output.
// CSR built per call; u = dinv*(h@W) pre-scale, CSR gather sums, post-scale
// by dinv[dst], self-loop folded as +u[d]. Layer1/4 transform BEFORE agg.
// R3: W1 in LDS + 4-way k-split + partial reduce (740->623us).
// R5: chunked agg16 + t768 dbuf REGRESSED (623->654) -> reverted to R3 forms.
// R6: k_fill was write-density-bound (207MB HBM for 12.8MB col, ~1TB/s wall,
//     VALU 0.5%). Two-level bucket CSR build: LDS-atomic ranking, per-bucket
//     contiguous writes -> L2-merged dense evictions; no global atomic-returns.

#define DIVUP(a, b) (((a) + (b) - 1) / (b))
#define NBUCK 128
#define BSHIFT 10            // bucket = dst >> 10 (1024 dst values per bucket)
#define BCAP 36864           // per-bucket capacity (mean 32768, +22 sigma)

// ---------- edge dtype detection (int64 vs int32 ABI ambiguity) ----------
__global__ void k_detect(const void* ei, int* flag) {
    int t = threadIdx.x;  // 64 threads
    const int* p = (const int*)ei;
    bool z = (p[2 * t + 1] == 0);
    unsigned long long m = __ballot(z);
    if (t == 0) *flag = (m == ~0ULL) ? 1 : 0;
}

__device__ __forceinline__ int load_idx(const void* ei, int is64, size_t pos) {
    if (is64) return (int)((const long long*)ei)[pos];
    return ((const int*)ei)[pos];
}

__global__ void k_zero(int* gcur) { gcur[threadIdx.x] = 0; }  // 128 threads

// ---------- pass 1: bucket edges by dst>>10, per-(block,bucket) dense runs ----------
__global__ void k_bucket(const void* ei, const int* flag, int* gcur,
                         int2* ebuf, int E) {
    __shared__ int hist[NBUCK];
    __shared__ int base[NBUCK];
    int tid = threadIdx.x;
    if (tid < NBUCK) hist[tid] = 0;
    __syncthreads();
    int is64 = *flag;
    int ebase = blockIdx.x * 2048 + tid;
    int s[8], d[8], r[8], bk[8];
    bool ok[8];
#pragma unroll
    for (int j = 0; j < 8; ++j) {
        int e = ebase + j * 256;
        ok[j] = (e < E);
        s[j] = ok[j] ? load_idx(ei, is64, (size_t)e) : 0;
        d[j] = ok[j] ? load_idx(ei, is64, (size_t)E + e) : 0;
        bk[j] = d[j] >> BSHIFT;
    }
#pragma unroll
    for (int j = 0; j < 8; ++j)
        r[j] = ok[j] ? atomicAdd(&hist[bk[j]], 1) : 0;
    __syncthreads();
    if (tid < NBUCK && hist[tid] > 0)
        base[tid] = atomicAdd(&gcur[tid], hist[tid]);
    __syncthreads();
#pragma unroll
    for (int j = 0; j < 8; ++j)
        if (ok[j])
            ebuf[(size_t)bk[j] * BCAP + base[bk[j]] + r[j]] = make_int2(s[j], d[j]);
}

// ---------- pass 2a: per-bucket degree histogram (LDS), dense cnt writes ----------
__global__ void k_hist(const int2* __restrict__ ebuf, const int* __restrict__ gcur,
                       int* __restrict__ cnt, int n) {
    __shared__ int deg[1024];
    int b = blockIdx.x, tid = threadIdx.x;  // 512 threads
    for (int j = tid; j < 1024; j += 512) deg[j] = 0;
    __syncthreads();
    int S = gcur[b], lo = b << BSHIFT;
    const int2* eb = ebuf + (size_t)b * BCAP;
    for (int i = tid; i < S; i += 2048) {
        int2 e0, e1, e2, e3;
        bool o1 = i + 512 < S, o2 = i + 1024 < S, o3 = i + 1536 < S;
        e0 = eb[i];
        e1 = o1 ? eb[i + 512] : e0;
        e2 = o2 ? eb[i + 1024] : e0;
        e3 = o3 ? eb[i + 1536] : e0;
        atomicAdd(&deg[e0.y - lo], 1);
        if (o1) atomicAdd(&deg[e1.y - lo], 1);
        if (o2) atomicAdd(&deg[e2.y - lo], 1);
        if (o3) atomicAdd(&deg[e3.y - lo], 1);
    }
    __syncthreads();
    for (int j = tid; j < 1024; j += 512)
        if (lo + j < n) cnt[lo + j] = deg[j];
}

// ---------- exclusive scan (3-phase) ----------
__global__ void k_scanA(const int* cnt, int* offs, int* bsums, int n) {
    __shared__ int s[256];
    int t = threadIdx.x;
    int i = blockIdx.x * 256 + t;
    int v = (i < n) ? cnt[i] : 0;
    s[t] = v;
    __syncthreads();
    for (int off = 1; off < 256; off <<= 1) {
        int add = (t >= off) ? s[t - off] : 0;
        __syncthreads();
        s[t] += add;
        __syncthreads();
    }
    if (i < n) offs[i] = s[t] - v;
    if (t == 255) bsums[blockIdx.x] = s[t];
}

__global__ void k_scanB(int* bsums, int nb) {
    __shared__ int s[512];
    int t = threadIdx.x;
    int v = (t < nb) ? bsums[t] : 0;
    s[t] = v;
    __syncthreads();
    for (int off = 1; off < 512; off <<= 1) {
        int add = (t >= off) ? s[t - off] : 0;
        __syncthreads();
        s[t] += add;
        __syncthreads();
    }
    if (t < nb) bsums[t] = s[t] - v;
}

__global__ void k_scanC(int* offs, const int* bsums, const int* cnt, float* dinv, int n) {
    int i = blockIdx.x * 256 + threadIdx.x;
    if (i >= n) return;
    offs[i] += bsums[blockIdx.x];
    dinv[i] = rsqrtf((float)(cnt[i] + 1));  // +1 self-loop
}

// ---------- pass 2b: CSR fill via LDS cursors, col writes in 130KB window ----------
__global__ void k_fillb(const int2* __restrict__ ebuf, const int* __restrict__ gcur,
                        const int* __restrict__ offs, int* __restrict__ col, int n) {
    __shared__ int cur[1024];
    int b = blockIdx.x, tid = threadIdx.x;  // 512 threads
    int lo = b << BSHIFT;
    for (int j = tid; j < 1024; j += 512)
        cur[j] = (lo + j < n) ? offs[lo + j] : 0;
    __syncthreads();
    int S = gcur[b];
    const int2* eb = ebuf + (size_t)b * BCAP;
    for (int i = tid; i < S; i += 2048) {
        int2 e0, e1, e2, e3;
        bool o1 = i + 512 < S, o2 = i + 1024 < S, o3 = i + 1536 < S;
        e0 = eb[i];
        e1 = o1 ? eb[i + 512] : e0;
        e2 = o2 ? eb[i + 1024] : e0;
        e3 = o3 ? eb[i + 1536] : e0;
        int p0 = atomicAdd(&cur[e0.y - lo], 1);
        int p1 = o1 ? atomicAdd(&cur[e1.y - lo], 1) : 0;
        int p2 = o2 ? atomicAdd(&cur[e2.y - lo], 1) : 0;
        int p3 = o3 ? atomicAdd(&cur[e3.y - lo], 1) : 0;
        col[p0] = e0.x;
        if (o1) col[p1] = e1.x;
        if (o2) col[p2] = e2.x;
        if (o3) col[p3] = e3.x;
    }
}

__device__ __forceinline__ void fma4(float s, const float4 w, float4& a) {
    a.x = fmaf(s, w.x, a.x);
    a.y = fmaf(s, w.y, a.y);
    a.z = fmaf(s, w.z, a.z);
    a.w = fmaf(s, w.w, a.w);
}

// ---------- layer-1 transform, k-split (R3 form): part = x[:,slice] @ W1[slice] ----------
__global__ void k_transform768(const float* __restrict__ x, const float* __restrict__ W,
                               float* __restrict__ parts, int n) {
    __shared__ float Wl[192 * 20];      // 15360 B
    __shared__ float lx[4][16][68];     // 17408 B
    int slice = blockIdx.x & 3;
    int nblk = blockIdx.x >> 2;
    int tid = threadIdx.x;
    int wid = tid >> 6, lane = tid & 63;
    int nbase = nblk * 64 + wid * 16;
    int nloc = lane >> 2, og = lane & 3;
    int node = nbase + nloc;
    const float4* xg = (const float4*)x;
    const float4* wg = (const float4*)W;

#pragma unroll
    for (int i = tid; i < 768; i += 256) {
        float4 v = wg[slice * 768 + i];
        int k = i >> 2, g = i & 3;
        *(float4*)&Wl[k * 20 + g * 4] = v;
    }
    __syncthreads();

    float4 acc = {0.f, 0.f, 0.f, 0.f};
    const float* lxr = lx[wid][nloc];
#pragma unroll 1
    for (int t = 0; t < 3; ++t) {
#pragma unroll
        for (int r = 0; r < 4; ++r) {
            int f = r * 64 + lane;
            int srow = f >> 4, scol = f & 15;
            int nb = nbase + srow;
            if (nb < n) {
                float4 v = xg[(size_t)nb * 192 + slice * 48 + t * 16 + scol];
                *(float4*)&lx[wid][srow][scol * 4] = v;
            }
        }
#pragma unroll 4
        for (int kk = 0; kk < 16; ++kk) {
            float4 xv = *(const float4*)&lxr[kk * 4];
            int kb = (t * 16 + kk) * 4;
            fma4(xv.x, *(const float4*)&Wl[(kb + 0) * 20 + og * 4], acc);
            fma4(xv.y, *(const float4*)&Wl[(kb + 1) * 20 + og * 4], acc);
            fma4(xv.z, *(const float4*)&Wl[(kb + 2) * 20 + og * 4], acc);
            fma4(xv.w, *(const float4*)&Wl[(kb + 3) * 20 + og * 4], acc);
        }
    }
    if (node < n) {
        float4* dst = (float4*)(parts + (size_t)slice * n * 16);
        dst[(size_t)node * 4 + og] = acc;
    }
}

// ---------- reduce 4 partials, apply dinv ----------
__global__ void k_red4(const float* __restrict__ parts, const float* __restrict__ dinv,
                       float* __restrict__ u, int n) {
    int g = blockIdx.x * 256 + threadIdx.x;
    if (g >= 4 * n) return;
    size_t stride = (size_t)n * 4;
    const float4* p = (const float4*)parts;
    float4 a = p[g], b = p[g + stride], c = p[g + 2 * stride], d = p[g + 3 * stride];
    float s = dinv[g >> 2];
    float4 r;
    r.x = (a.x + b.x + c.x + d.x) * s;
    r.y = (a.y + b.y + c.y + d.y) * s;
    r.z = (a.z + b.z + c.z + d.z) * s;
    r.w = (a.w + b.w + c.w + d.w) * s;
    ((float4*)u)[g] = r;
}

// ---------- 16->16 transform ----------
__global__ void k_transform16(const float* __restrict__ in, const float* __restrict__ W,
                              const float* __restrict__ dinv, float* __restrict__ out, int n) {
    int gid = blockIdx.x * 256 + threadIdx.x;
    int node = gid >> 2, og = gid & 3;
    if (node >= n) return;
    const float4* xr = (const float4*)(in + (size_t)node * 16);
    const float4* w4 = (const float4*)W;
    float4 acc = {0.f, 0.f, 0.f, 0.f};
#pragma unroll
    for (int kk = 0; kk < 4; ++kk) {
        float4 xv = xr[kk];
        int k4 = kk * 16;
        fma4(xv.x, w4[k4 + og], acc);
        fma4(xv.y, w4[k4 + 4 + og], acc);
        fma4(xv.z, w4[k4 + 8 + og], acc);
        fma4(xv.w, w4[k4 + 12 + og], acc);
    }
    float s = dinv[node];
    float4 r = {acc.x * s, acc.y * s, acc.z * s, acc.w * s};
    ((float4*)out)[(size_t)node * 4 + og] = r;
}

// ---------- layer-4 transform (vectorized loads) ----------
__global__ void k_t4(const float* __restrict__ h, const float* __restrict__ W4,
                     const float* __restrict__ dinv, float4* __restrict__ u4p, int n) {
    int node = blockIdx.x * 256 + threadIdx.x;
    if (node >= n) return;
    const float4* hr = (const float4*)(h + (size_t)node * 16);
    float4 h0 = hr[0], h1 = hr[1], h2 = hr[2], h3 = hr[3];
    float hv[16] = {h0.x, h0.y, h0.z, h0.w, h1.x, h1.y, h1.z, h1.w,
                    h2.x, h2.y, h2.z, h2.w, h3.x, h3.y, h3.z, h3.w};
    float a0 = 0.f, a1 = 0.f, a2 = 0.f;
#pragma unroll
    for (int k = 0; k < 16; ++k) {
        a0 = fmaf(hv[k], W4[k * 3 + 0], a0);
        a1 = fmaf(hv[k], W4[k * 3 + 1], a1);
        a2 = fmaf(hv[k], W4[k * 3 + 2], a2);
    }
    float s = dinv[node];
    u4p[node] = make_float4(a0 * s, a1 * s, a2 * s, 0.f);
}

// ---------- aggregate 16-dim (R3 form, 4-deep strided MLP) ----------
__global__ void k_agg16(const float* __restrict__ u, const int* __restrict__ col,
                        const int* __restrict__ offs, const int* __restrict__ cnt,
                        const float* __restrict__ dinv, const float* __restrict__ b,
                        float* __restrict__ hout, int n) {
    int wave = threadIdx.x >> 6;
    int node = blockIdx.x * 4 + wave;
    if (node >= n) return;
    int lane = threadIdx.x & 63;
    int eslot = lane >> 2, comp = lane & 3;
    const float4* u4 = (const float4*)u;
    int beg = offs[node], c = cnt[node];
    float4 a0 = {0.f, 0.f, 0.f, 0.f}, a1 = a0, a2 = a0, a3 = a0;
    int i = eslot;
    for (; i + 48 < c; i += 64) {
        int s0 = col[beg + i];
        int s1 = col[beg + i + 16];
        int s2 = col[beg + i + 32];
        int s3 = col[beg + i + 48];
        float4 v0 = u4[(size_t)s0 * 4 + comp];
        float4 v1 = u4[(size_t)s1 * 4 + comp];
        float4 v2 = u4[(size_t)s2 * 4 + comp];
        float4 v3 = u4[(size_t)s3 * 4 + comp];
        a0.x += v0.x; a0.y += v0.y; a0.z += v0.z; a0.w += v0.w;
        a1.x += v1.x; a1.y += v1.y; a1.z += v1.z; a1.w += v1.w;
        a2.x += v2.x; a2.y += v2.y; a2.z += v2.z; a2.w += v2.w;
        a3.x += v3.x; a3.y += v3.y; a3.z += v3.z; a3.w += v3.w;
    }
    for (; i < c; i += 16) {
        int s0 = col[beg + i];
        float4 v0 = u4[(size_t)s0 * 4 + comp];
        a0.x += v0.x; a0.y += v0.y; a0.z += v0.z; a0.w += v0.w;
    }
    a0.x += a1.x + a2.x + a3.x;
    a0.y += a1.y + a2.y + a3.y;
    a0.z += a1.z + a2.z + a3.z;
    a0.w += a1.w + a2.w + a3.w;
    for (int off = 4; off < 64; off <<= 1) {
        a0.x += __shfl_xor(a0.x, off, 64);
        a0.y += __shfl_xor(a0.y, off, 64);
        a0.z += __shfl_xor(a0.z, off, 64);
        a0.w += __shfl_xor(a0.w, off, 64);
    }
    if (eslot == 0) {
        float4 self = u4[(size_t)node * 4 + comp];
        float dv = dinv[node];
        float4 bb = ((const float4*)b)[comp];
        float4 r;
        r.x = fmaxf(fmaf(dv, a0.x + self.x, bb.x), 0.f);
        r.y = fmaxf(fmaf(dv, a0.y + self.y, bb.y), 0.f);
        r.z = fmaxf(fmaf(dv, a0.z + self.z, bb.z), 0.f);
        r.w = fmaxf(fmaf(dv, a0.w + self.w, bb.w), 0.f);
        ((float4*)hout)[(size_t)node * 4 + comp] = r;
    }
}

// ---------- final aggregate (3 dims) + bias + log_softmax ----------
__global__ void k_agg_out(const float4* __restrict__ u4p, const int* __restrict__ col,
                          const int* __restrict__ offs, const int* __restrict__ cnt,
                          const float* __restrict__ dinv, const float* __restrict__ b4,
                          float* __restrict__ out, int n) {
    int wave = threadIdx.x >> 6;
    int node = blockIdx.x * 4 + wave;
    if (node >= n) return;
    int lane = threadIdx.x & 63;
    int beg = offs[node], c = cnt[node];
    float a0 = 0.f, a1 = 0.f, a2 = 0.f;
    for (int i = lane; i < c; i += 64) {
        float4 v = u4p[col[beg + i]];
        a0 += v.x; a1 += v.y; a2 += v.z;
    }
    for (int off = 1; off < 64; off <<= 1) {
        a0 += __shfl_xor(a0, off, 64);
        a1 += __shfl_xor(a1, off, 64);
        a2 += __shfl_xor(a2, off, 64);
    }
    if (lane == 0) {
        float4 self = u4p[node];
        float dv = dinv[node];
        float v0 = fmaf(dv, a0 + self.x, b4[0]);
        float v1 = fmaf(dv, a1 + self.y, b4[1]);
        float v2 = fmaf(dv, a2 + self.z, b4[2]);
        float m = fmaxf(v0, fmaxf(v1, v2));
        float lse = m + logf(expf(v0 - m) + expf(v1 - m) + expf(v2 - m));
        out[(size_t)node * 3 + 0] = v0 - lse;
        out[(size_t)node * 3 + 1] = v1 - lse;
        out[(size_t)node * 3 + 2] = v2 - lse;
    }
}

extern "C" void kernel_launch(void* const* d_in, const int* in_sizes, int n_in,
                              void* d_out, int out_size, void* d_ws, size_t ws_size,
                              hipStream_t stream) {
    const float* x  = (const float*)d_in[0];
    const void*  ei = d_in[1];
    const float* W1 = (const float*)d_in[2];
    const float* b1 = (const float*)d_in[3];
    const float* W2 = (const float*)d_in[4];
    const float* b2 = (const float*)d_in[5];
    const float* W3 = (const float*)d_in[6];
    const float* b3 = (const float*)d_in[7];
    const float* W4 = (const float*)d_in[8];
    const float* b4 = (const float*)d_in[9];
    float* out = (float*)d_out;

    const int N = in_sizes[0] / 768;
    const int E = in_sizes[1] / 2;

    char* p = (char*)d_ws;
    auto alloc = [&](size_t bytes) {
        void* r = (void*)p;
        p += (bytes + 255) & ~(size_t)255;
        return r;
    };
    int*   cnt   = (int*)alloc((size_t)N * 4);
    int*   offs  = (int*)alloc((size_t)N * 4);
    int*   bsums = (int*)alloc(4096);
    int*   flag  = (int*)alloc(256);
    int*   gcur  = (int*)alloc(1024);
    float* dinv  = (float*)alloc((size_t)N * 4);
    int*   col   = (int*)alloc((size_t)E * 4);
    float* u     = (float*)alloc((size_t)N * 16 * 4);
    float* h     = (float*)alloc((size_t)N * 16 * 4);
    float4* u4p  = (float4*)alloc((size_t)N * 16);
    // ebuf (CSR build) and parts (layer-1) have disjoint lifetimes -> union
    void* big    = alloc((size_t)NBUCK * BCAP * 8);
    int2*  ebuf  = (int2*)big;
    float* parts = (float*)big;

    const int nbN = DIVUP(N, 256);
    const int nbB = DIVUP(E, 2048);
    const int nbT = DIVUP(4 * N, 256);
    const int nbA = DIVUP(N, 4);
    const int nbX = DIVUP(N, 64) * 4;

    // CSR build: bucket -> hist -> scan -> fill
    k_detect<<<1, 64, 0, stream>>>(ei, flag);
    k_zero<<<1, 128, 0, stream>>>(gcur);
    k_bucket<<<nbB, 256, 0, stream>>>(ei, flag, gcur, ebuf, E);
    k_hist<<<NBUCK, 512, 0, stream>>>(ebuf, gcur, cnt, N);
    k_scanA<<<nbN, 256, 0, stream>>>(cnt, offs, bsums, N);
    k_scanB<<<1, 512, 0, stream>>>(bsums, nbN);
    k_scanC<<<nbN, 256, 0, stream>>>(offs, bsums, cnt, dinv, N);
    k_fillb<<<NBUCK, 512, 0, stream>>>(ebuf, gcur, offs, col, N);

    // layer 1 (note: t768 must run AFTER k_fillb since parts aliases ebuf)
    k_transform768<<<nbX, 256, 0, stream>>>(x, W1, parts, N);
    k_red4<<<nbT, 256, 0, stream>>>(parts, dinv, u, N);
    k_agg16<<<nbA, 256, 0, stream>>>(u, col, offs, cnt, dinv, b1, h, N);
    // layer 2
    k_transform16<<<nbT, 256, 0, stream>>>(h, W2, dinv, u, N);
    k_agg16<<<nbA, 256, 0, stream>>>(u, col, offs, cnt, dinv, b2, h, N);
    // layer 3
    k_transform16<<<nbT, 256, 0, stream>>>(h, W3, dinv, u, N);
    k_agg16<<<nbA, 256, 0, stream>>>(u, col, offs, cnt, dinv, b3, h, N);
    // layer 4
    k_t4<<<nbN, 256, 0, stream>>>(h, W4, dinv, u4p, N);
    k_agg_out<<<nbA, 256, 0, stream>>>(u4p, col, offs, cnt, dinv, b4, out, N);
}